// Round 1
// baseline (343.562 us; speedup 1.0000x reference)
//
#include <hip/hip_runtime.h>

#define NU 4096
#define NI 4096
#define NE 128
#define NR 3
#define NB 512
#define NL 100
#define FEPS 1e-8f

// workspace layout (float offsets)
#define WS_SI    0            // [NI*128]   s_i transposed: [i][k*32+d]
#define WS_TIP   524288       // [3*NI*128] tip per relation
#define WS_PRE   2097152      // [NI*128]   train_matrix.T @ user_embedding
#define WS_ITEMF 2621440      // [NI*128]   item_feature
#define WS_WTUN  3145728      // [NB*3*128] ubw-weighted tun per (b,r)
#define WS_PROJ  3342336      // [NB*3*128] proj per (b,r)
#define WS_UF    3538944      // [NB*128]   uf_sel
#define WS_UF2P  3604480      // [NB]       per-b uf^2 partials
#define WS_ITF2P 3604992      // [12800]    per-block itf^2 partials

// ---------------------------------------------------------------------------
// K1: s_i[i][t] = l2norm_D(relu(W_K @ item_emb[i] + B_K)), t = k*32+d
__global__ void k_si(const float* __restrict__ iemb, const float* __restrict__ WK,
                     const float* __restrict__ BK, float* __restrict__ si) {
  int i = blockIdx.x;
  __shared__ __align__(16) float embs[128];
  int t = threadIdx.x;  // 128
  if (t < 32) ((float4*)embs)[t] = ((const float4*)(iemb + (size_t)i * 128))[t];
  __syncthreads();
  float acc = BK[t];
  const float4* wk4 = (const float4*)(WK + (size_t)t * 128);
  const float4* e4 = (const float4*)embs;
#pragma unroll 8
  for (int c = 0; c < 32; ++c) {
    float4 w = wk4[c], v = e4[c];
    acc += w.x * v.x + w.y * v.y + w.z * v.z + w.w * v.w;
  }
  acc = fmaxf(acc, 0.f);
  float sq = acc * acc;
#pragma unroll
  for (int m = 1; m <= 16; m <<= 1) sq += __shfl_xor(sq, m);  // reduce over D=32 group
  si[(size_t)i * 128 + t] = acc / fmaxf(sqrtf(sq), 1e-12f);
}

// ---------------------------------------------------------------------------
// K2: per (r,i): agg = (item_graphs[r][i,:] @ item_emb)/(deg+eps); tip = agg @ ipW[r]
__global__ void k_agg_tip(const float* __restrict__ G, const float* __restrict__ emb,
                          const float* __restrict__ deg, const float* __restrict__ ipW,
                          float* __restrict__ tip) {
  int bid = blockIdx.x;  // r*4096 + i
  int r = bid >> 12;
  const float* row = G + (size_t)bid * NI;
  __shared__ int nz[512];
  __shared__ int cnt;
  __shared__ float comb[2][128];
  __shared__ float aggrow[128];
  int t = threadIdx.x;  // 256
  if (t == 0) cnt = 0;
  __syncthreads();
  const float4* row4 = (const float4*)row;
  for (int c = 0; c < 4; ++c) {
    int idx4 = c * 256 + t;
    float4 v = row4[idx4];
    int j0 = idx4 << 2;
    if (v.x != 0.f) nz[atomicAdd(&cnt, 1)] = j0;
    if (v.y != 0.f) nz[atomicAdd(&cnt, 1)] = j0 + 1;
    if (v.z != 0.f) nz[atomicAdd(&cnt, 1)] = j0 + 2;
    if (v.w != 0.f) nz[atomicAdd(&cnt, 1)] = j0 + 3;
  }
  __syncthreads();
  int n = min(cnt, 512);  // binomial(4096,0.01): >512 impossible in practice
  int e = t & 127, half = t >> 7;
  float acc = 0.f;
  for (int p = half; p < n; p += 2) acc += emb[(size_t)nz[p] * 128 + e];  // values are exactly 1.0
  comb[half][e] = acc;
  __syncthreads();
  if (half == 0) aggrow[e] = (comb[0][e] + comb[1][e]) / (deg[bid] + FEPS);
  __syncthreads();
  const float* Wp = ipW + (size_t)r * 16384;
  float pacc = 0.f;
  for (int ee = half * 64; ee < half * 64 + 64; ++ee) pacc += aggrow[ee] * Wp[ee * 128 + e];
  comb[half][e] = pacc;
  __syncthreads();
  if (half == 0) tip[(size_t)bid * 128 + e] = comb[0][e] + comb[1][e];
}

// ---------------------------------------------------------------------------
// K3: pre[i][e] = sum_u tm[u][i]*ue[u][e]  (sparse column-tile accumulation)
__global__ void k_pre(const float* __restrict__ tm, const float* __restrict__ ue,
                      float* __restrict__ pre) {
  int ct = blockIdx.x & 63, rs = blockIdx.x >> 6;  // 64 col-tiles x 8 row-splits
  __shared__ float acc[64][128];                   // 32 KB
  int t = threadIdx.x;                             // 256
  for (int i = t; i < 8192; i += 256) ((float*)acc)[i] = 0.f;
  __syncthreads();
  int wid = t >> 6, lane = t & 63;
  int col0 = ct << 6;
  for (int itn = 0; itn < 128; ++itn) {
    int u = (rs << 9) + (itn << 2) + wid;
    float v = tm[(size_t)u * NI + col0 + lane];
    unsigned long long mask = __ballot(v != 0.f);
    while (mask) {
      int src = __ffsll(mask) - 1;
      mask &= mask - 1;
      float vs = __shfl(v, src);
      float a0 = ue[(size_t)u * 128 + lane];
      float a1 = ue[(size_t)u * 128 + 64 + lane];
      atomicAdd(&acc[src][lane], vs * a0);
      atomicAdd(&acc[src][64 + lane], vs * a1);
    }
  }
  __syncthreads();
  for (int i = t; i < 8192; i += 256) atomicAdd(&pre[(size_t)col0 * 128 + i], ((float*)acc)[i]);
}

// ---------------------------------------------------------------------------
// K4: itemf = pre @ W   ([4096,128] x [128,128])
__global__ void k_itemf(const float* __restrict__ pre, const float* __restrict__ Wm,
                        float* __restrict__ itemf) {
  int rb = blockIdx.x;  // 256 blocks x 16 rows
  __shared__ __align__(16) float inl[16][128];
  int t = threadIdx.x;  // 256
  const float4* in4 = (const float4*)(pre + (size_t)rb * 16 * 128);
  for (int c = t; c < 512; c += 256) ((float4*)inl)[c] = in4[c];
  __syncthreads();
  int c = t & 127, g = t >> 7;
  float acc[8];
#pragma unroll
  for (int rr = 0; rr < 8; ++rr) acc[rr] = 0.f;
  for (int e = 0; e < 128; ++e) {
    float wv = Wm[e * 128 + c];
#pragma unroll
    for (int rr = 0; rr < 8; ++rr) acc[rr] += inl[g * 8 + rr][e] * wv;
  }
#pragma unroll
  for (int rr = 0; rr < 8; ++rr) itemf[((size_t)rb * 16 + g * 8 + rr) * 128 + c] = acc[rr];
}

// ---------------------------------------------------------------------------
// K5: per (b,r): scan rel row, on-the-fly softmax over K per neighbor item,
// accumulate s_u and rel@tip; emit ubw-weighted tun and proj.
__global__ void k_user(const int* __restrict__ user, const float* __restrict__ relm,
                       const float* __restrict__ si, const float* __restrict__ tip,
                       const float* __restrict__ uemb, const float* __restrict__ WK,
                       const float* __restrict__ BK, const float* __restrict__ ibW,
                       const float* __restrict__ ubd, const float* __restrict__ mw,
                       float* __restrict__ wtun, float* __restrict__ proj) {
  int bid = blockIdx.x;
  int r = bid >> 9, b = bid & 511;
  int u = user[b];
  const float* rel = relm + ((size_t)r * NU + u) * NI;
  __shared__ int nz[512];
  __shared__ int cnt;
  __shared__ __align__(16) float uel[128];
  __shared__ float redA[4][128];
  __shared__ float redB[4][128];
  __shared__ float tu[128];
  int t = threadIdx.x;  // 256
  if (t == 0) cnt = 0;
  if (t < 32) ((float4*)uel)[t] = ((const float4*)(uemb + (size_t)u * 128))[t];
  __syncthreads();
  const float4* rel4 = (const float4*)rel;
  for (int c = 0; c < 4; ++c) {
    int idx4 = c * 256 + t;
    float4 v = rel4[idx4];
    int j0 = idx4 << 2;
    if (v.x != 0.f) nz[atomicAdd(&cnt, 1)] = j0;
    if (v.y != 0.f) nz[atomicAdd(&cnt, 1)] = j0 + 1;
    if (v.z != 0.f) nz[atomicAdd(&cnt, 1)] = j0 + 2;
    if (v.w != 0.f) nz[atomicAdd(&cnt, 1)] = j0 + 3;
  }
  __syncthreads();
  int n = min(cnt, 512);
  int wid = t >> 6, lane = t & 63;
  int k = lane >> 4;  // head: 16 lanes per head, float2 per lane covers D=32
  float2 myue = ((const float2*)uel)[lane];
  float sux = 0.f, suy = 0.f, tpx = 0.f, tpy = 0.f;
  const float2* si2 = (const float2*)si;
  const float2* tip2 = (const float2*)(tip + (size_t)r * NI * 128);
  for (int p = wid; p < n; p += 4) {
    int i = nz[p];
    float2 sv = si2[(size_t)i * 64 + lane];
    float lg = myue.x * sv.x + myue.y * sv.y;  // logit partial, own head
    lg += __shfl_xor(lg, 1);
    lg += __shfl_xor(lg, 2);
    lg += __shfl_xor(lg, 4);
    lg += __shfl_xor(lg, 8);
    float l0 = __shfl(lg, 0), l1 = __shfl(lg, 16), l2 = __shfl(lg, 32), l3 = __shfl(lg, 48);
    float mx = fmaxf(fmaxf(l0, l1), fmaxf(l2, l3));
    float e0 = __expf(l0 - mx), e1 = __expf(l1 - mx), e2 = __expf(l2 - mx), e3 = __expf(l3 - mx);
    float inv = 1.f / (e0 + e1 + e2 + e3);
    float myr = (k == 0 ? e0 : k == 1 ? e1 : k == 2 ? e2 : e3) * inv;
    sux += myr * sv.x;
    suy += myr * sv.y;
    float2 tv = tip2[(size_t)i * 64 + lane];
    tpx += tv.x;
    tpy += tv.y;
  }
  redA[wid][2 * lane] = sux; redA[wid][2 * lane + 1] = suy;
  redB[wid][2 * lane] = tpx; redB[wid][2 * lane + 1] = tpy;
  __syncthreads();
  if (t < 128) {
    float suv = redA[0][t] + redA[1][t] + redA[2][t] + redA[3][t];
    float tipv = redB[0][t] + redB[1][t] + redB[2][t] + redB[3][t];
    // s_u0 for this user (recomputed per relation; 16K FMA, negligible)
    float a = BK[t];
    const float4* wk4 = (const float4*)(WK + (size_t)t * 128);
    const float4* ue4 = (const float4*)uel;
#pragma unroll 8
    for (int c = 0; c < 32; ++c) {
      float4 w = wk4[c], v = ue4[c];
      a += w.x * v.x + w.y * v.y + w.z * v.z + w.w * v.w;
    }
    a = fmaxf(a, 0.f);
    float sq = a * a;
#pragma unroll
    for (int m = 1; m <= 16; m <<= 1) sq += __shfl_xor(sq, m);
    float su = a / fmaxf(sqrtf(sq), 1e-12f) + suv;
    float sq2 = su * su;
#pragma unroll
    for (int m = 1; m <= 16; m <<= 1) sq2 += __shfl_xor(sq2, m);
    float tun = su / fmaxf(sqrtf(sq2), 1e-12f);
    float d0 = ubd[u * 3], d1 = ubd[u * 3 + 1], d2 = ubd[u * 3 + 2];
    float w0 = mw[0], w1 = mw[1], w2 = mw[2];
    float tw = d0 * w0 + d1 * w1 + d2 * w2;
    float dr = (r == 0 ? d0 : r == 1 ? d1 : d2);
    float wr = (r == 0 ? w0 : r == 1 ? w1 : w2);
    wtun[(size_t)(b * 3 + r) * 128 + t] = (dr * wr / (tw + FEPS)) * tun;
    tu[t] = tipv / (dr + FEPS);  // tuinp
  }
  __syncthreads();
  // proj = tuinp @ item_behaviour_W[r]
  int ep = t & 127, hh = t >> 7;
  const float* Wb = ibW + (size_t)r * 16384;
  float pacc = 0.f;
  for (int e = hh * 64; e < hh * 64 + 64; ++e) pacc += tu[e] * Wb[e * 128 + ep];
  redA[hh][ep] = pacc;  // reuse
  __syncthreads();
  if (hh == 0) proj[(size_t)(b * 3 + r) * 128 + ep] = redA[0][ep] + redA[1][ep];
}

// ---------------------------------------------------------------------------
// K6: uf[b] = (sum_r wtun[b,r]) @ W ; per-b uf^2 partial
__global__ void k_uf(const float* __restrict__ wtun, const float* __restrict__ Wm,
                     float* __restrict__ uf, float* __restrict__ uf2p) {
  int b = blockIdx.x, t = threadIdx.x;  // 128
  __shared__ float comb[128];
  __shared__ float part[2];
  comb[t] = wtun[(size_t)(b * 3) * 128 + t] + wtun[(size_t)(b * 3 + 1) * 128 + t] +
            wtun[(size_t)(b * 3 + 2) * 128 + t];
  __syncthreads();
  float acc = 0.f;
  for (int e = 0; e < 128; ++e) acc += comb[e] * Wm[e * 128 + t];
  uf[(size_t)b * 128 + t] = acc;
  float sq = acc * acc;
#pragma unroll
  for (int m = 1; m <= 32; m <<= 1) sq += __shfl_xor(sq, m);
  if ((t & 63) == 0) part[t >> 6] = sq;
  __syncthreads();
  if (t == 0) uf2p[b] = part[0] + part[1];
}

// ---------------------------------------------------------------------------
// K7: one wave per (b,l): score1 + LAMB*score2/R ; itf^2 partial per block
__global__ void k_score(const int* __restrict__ item, const float* __restrict__ itemf,
                        const float* __restrict__ uf, const float* __restrict__ tip,
                        const float* __restrict__ proj, float* __restrict__ out,
                        float* __restrict__ itf2p) {
  int t = threadIdx.x, wid = t >> 6, lane = t & 63;
  int idx = blockIdx.x * 4 + wid;  // < 51200
  int b = idx / NL;
  int it = item[idx];
  float2 av = ((const float2*)(itemf + (size_t)it * 128))[lane];
  float2 cv = ((const float2*)(uf + (size_t)b * 128))[lane];
  float s1 = av.x * cv.x + av.y * cv.y;
  float sqi = av.x * av.x + av.y * av.y;
  float s2 = 0.f;
#pragma unroll
  for (int r = 0; r < 3; ++r) {
    float2 tv = ((const float2*)(tip + ((size_t)r * NI + it) * 128))[lane];
    float2 pv = ((const float2*)(proj + (size_t)(b * 3 + r) * 128))[lane];
    s2 += tv.x * pv.x + tv.y * pv.y;
  }
#pragma unroll
  for (int m = 1; m <= 32; m <<= 1) {
    s1 += __shfl_xor(s1, m);
    s2 += __shfl_xor(s2, m);
    sqi += __shfl_xor(sqi, m);
  }
  if (lane == 0) out[idx] = s1 + 0.5f * (s2 * (1.f / 3.f));
  __shared__ float sh[4];
  if (lane == 0) sh[wid] = sqi;
  __syncthreads();
  if (t == 0) itf2p[blockIdx.x] = sh[0] + sh[1] + sh[2] + sh[3];
}

// ---------------------------------------------------------------------------
// K8: L2_loss = 1e-4 * (100 * sum uf^2 + sum itf^2)
__global__ void k_final(const float* __restrict__ itf2p, const float* __restrict__ uf2p,
                        float* __restrict__ out) {
  int t = threadIdx.x;  // 256
  float v = 0.f;
  for (int i = t; i < 12800; i += 256) v += itf2p[i];
  float vu = 0.f;
  for (int i = t; i < NB; i += 256) vu += uf2p[i];
  v += 100.f * vu;
#pragma unroll
  for (int m = 1; m <= 32; m <<= 1) v += __shfl_xor(v, m);
  __shared__ float sh[4];
  if ((t & 63) == 0) sh[t >> 6] = v;
  __syncthreads();
  if (t == 0) out[NB * NL] = 1e-4f * (sh[0] + sh[1] + sh[2] + sh[3]);
}

// ---------------------------------------------------------------------------
extern "C" void kernel_launch(void* const* d_in, const int* in_sizes, int n_in,
                              void* d_out, int out_size, void* d_ws, size_t ws_size,
                              hipStream_t stream) {
  (void)in_sizes; (void)n_in; (void)out_size; (void)ws_size;
  const int* user = (const int*)d_in[0];
  const int* item = (const int*)d_in[1];
  const float* uemb = (const float*)d_in[2];
  const float* iemb = (const float*)d_in[3];
  const float* mw = (const float*)d_in[4];
  const float* ibW = (const float*)d_in[5];
  const float* ipW = (const float*)d_in[6];
  const float* Wm = (const float*)d_in[7];
  const float* WK = (const float*)d_in[8];
  const float* BK = (const float*)d_in[9];
  const float* tm = (const float*)d_in[10];
  const float* relm = (const float*)d_in[11];
  const float* ig = (const float*)d_in[12];
  const float* igd = (const float*)d_in[13];
  const float* ubd = (const float*)d_in[14];
  float* out = (float*)d_out;
  float* ws = (float*)d_ws;

  hipMemsetAsync(ws + WS_PRE, 0, (size_t)NI * 128 * sizeof(float), stream);
  k_si<<<NI, 128, 0, stream>>>(iemb, WK, BK, ws + WS_SI);
  k_agg_tip<<<NR * NI, 256, 0, stream>>>(ig, iemb, igd, ipW, ws + WS_TIP);
  k_pre<<<512, 256, 0, stream>>>(tm, uemb, ws + WS_PRE);
  k_itemf<<<256, 256, 0, stream>>>(ws + WS_PRE, Wm, ws + WS_ITEMF);
  k_user<<<NR * NB, 256, 0, stream>>>(user, relm, ws + WS_SI, ws + WS_TIP, uemb, WK, BK,
                                      ibW, ubd, mw, ws + WS_WTUN, ws + WS_PROJ);
  k_uf<<<NB, 128, 0, stream>>>(ws + WS_WTUN, Wm, ws + WS_UF, ws + WS_UF2P);
  k_score<<<12800, 256, 0, stream>>>(item, ws + WS_ITEMF, ws + WS_UF, ws + WS_TIP,
                                     ws + WS_PROJ, out, ws + WS_ITF2P);
  k_final<<<1, 256, 0, stream>>>(ws + WS_ITF2P, ws + WS_UF2P, out);
}

// Round 2
// 307.646 us; speedup vs baseline: 1.1167x; 1.1167x over previous
//
#include <hip/hip_runtime.h>

#define NU 4096
#define NI 4096
#define NR 3
#define NB 512
#define NL 100
#define FEPS 1e-8f

// workspace layout (float offsets)
#define WS_SI    0            // [NI*128]   s_i: [i][k*32+d]
#define WS_AGG   524288       // [3*NI*128] graph-aggregated item emb per relation
#define WS_TIP   2097152      // [3*NI*128] tip per relation
#define WS_UEW   3670016      // [NU*128]   user_embedding @ W
#define WS_ITEMF 4194304      // [NI*128]   item_feature
#define WS_WTUN  4718592      // [NB*3*128] ubw-weighted tun per (b,r)
#define WS_PROJ  4915200      // [NB*3*128] proj per (b,r)
#define WS_UF    5111808      // [NB*128]   uf_sel
#define WS_UF2P  5177344      // [NB]       per-b uf^2 partials
#define WS_ITF2P 5177856      // [12800]    per-block itf^2 partials

// ---------------------------------------------------------------------------
// K1: s_i[i][t] = l2norm_D(relu(W_K @ item_emb[i] + B_K)), t = k*32+d
__global__ void k_si(const float* __restrict__ iemb, const float* __restrict__ WK,
                     const float* __restrict__ BK, float* __restrict__ si) {
  int i = blockIdx.x;
  __shared__ __align__(16) float embs[128];
  int t = threadIdx.x;  // 128
  if (t < 32) ((float4*)embs)[t] = ((const float4*)(iemb + (size_t)i * 128))[t];
  __syncthreads();
  float acc = BK[t];
  const float4* wk4 = (const float4*)(WK + (size_t)t * 128);
  const float4* e4 = (const float4*)embs;
#pragma unroll 8
  for (int c = 0; c < 32; ++c) {
    float4 w = wk4[c], v = e4[c];
    acc += w.x * v.x + w.y * v.y + w.z * v.z + w.w * v.w;
  }
  acc = fmaxf(acc, 0.f);
  float sq = acc * acc;
#pragma unroll
  for (int m = 1; m <= 16; m <<= 1) sq += __shfl_xor(sq, m);
  si[(size_t)i * 128 + t] = acc / fmaxf(sqrtf(sq), 1e-12f);
}

// ---------------------------------------------------------------------------
// K2: agg[r][i] = (item_graphs[r][i,:] @ item_emb) / (deg+eps)   (pure scan)
__global__ void k_agg(const float* __restrict__ G, const float* __restrict__ emb,
                      const float* __restrict__ deg, float* __restrict__ agg) {
  int bid = blockIdx.x;  // r*4096 + i
  const float4* row4 = (const float4*)(G + (size_t)bid * NI);
  __shared__ int nz[512];
  __shared__ int cnt;
  __shared__ float4 red[8][32];
  int t = threadIdx.x;  // 256
  if (t == 0) cnt = 0;
  __syncthreads();
#pragma unroll
  for (int c = 0; c < 4; ++c) {
    int idx4 = c * 256 + t;
    float4 v = row4[idx4];
    int j0 = idx4 << 2;
    if (v.x != 0.f) nz[atomicAdd(&cnt, 1)] = j0;
    if (v.y != 0.f) nz[atomicAdd(&cnt, 1)] = j0 + 1;
    if (v.z != 0.f) nz[atomicAdd(&cnt, 1)] = j0 + 2;
    if (v.w != 0.f) nz[atomicAdd(&cnt, 1)] = j0 + 3;
  }
  __syncthreads();
  int n = min(cnt, 512);
  int g = t >> 5, f = t & 31;  // 8 neighbor-slots x 32 lanes (float4 each)
  float4 acc = {0.f, 0.f, 0.f, 0.f};
  const float4* emb4 = (const float4*)emb;
  for (int p = g; p < n; p += 8) {
    float4 v = emb4[(size_t)nz[p] * 32 + f];
    acc.x += v.x; acc.y += v.y; acc.z += v.z; acc.w += v.w;
  }
  red[g][f] = acc;
  __syncthreads();
  if (t < 32) {
    float4 s = red[0][t];
#pragma unroll
    for (int q = 1; q < 8; ++q) {
      float4 v = red[q][t];
      s.x += v.x; s.y += v.y; s.z += v.z; s.w += v.w;
    }
    float inv = 1.f / (deg[bid] + FEPS);
    s.x *= inv; s.y *= inv; s.z *= inv; s.w *= inv;
    ((float4*)(agg + (size_t)bid * 128))[t] = s;
  }
}

// ---------------------------------------------------------------------------
// K3: batched dense [4096,128]@[128,128]: batches 0-2 tip=agg@ipW[r], batch 3 uew=uemb@W
__global__ void k_bmm(const float* __restrict__ agg, const float* __restrict__ ipW,
                      const float* __restrict__ uemb, const float* __restrict__ Wm,
                      float* __restrict__ tip, float* __restrict__ uew) {
  int batch = blockIdx.x >> 8, rb = blockIdx.x & 255;  // 16 rows per block
  const float* in;
  const float* Wp;
  float* out;
  if (batch < 3) {
    in = agg + (size_t)batch * NI * 128;
    Wp = ipW + (size_t)batch * 16384;
    out = tip + (size_t)batch * NI * 128;
  } else {
    in = uemb; Wp = Wm; out = uew;
  }
  __shared__ __align__(16) float inl[16][128];
  int t = threadIdx.x;  // 256
  const float4* in4 = (const float4*)(in + (size_t)rb * 2048);
  for (int c = t; c < 512; c += 256) ((float4*)inl)[c] = in4[c];
  __syncthreads();
  int c = t & 127, g = t >> 7;
  float acc[8];
#pragma unroll
  for (int rr = 0; rr < 8; ++rr) acc[rr] = 0.f;
  for (int e = 0; e < 128; ++e) {
    float wv = Wp[e * 128 + c];
#pragma unroll
    for (int rr = 0; rr < 8; ++rr) acc[rr] += inl[g * 8 + rr][e] * wv;
  }
#pragma unroll
  for (int rr = 0; rr < 8; ++rr) out[((size_t)rb * 16 + g * 8 + rr) * 128 + c] = acc[rr];
}

// ---------------------------------------------------------------------------
// K4: itemf += tm^T @ uew  (sparse col-tile scan; itemf pre-zeroed)
__global__ void k_preitemf(const float* __restrict__ tm, const float* __restrict__ uew,
                           float* __restrict__ itemf) {
  int ct = blockIdx.x & 63, rs = blockIdx.x >> 6;  // 64 col-tiles x 16 row-chunks
  int col0 = ct << 6, row0 = rs << 8;
  __shared__ float acc[64][128];  // 32 KB
  __shared__ int nz[512];
  __shared__ int cnt;
  int t = threadIdx.x;  // 256
  for (int i = t; i < 8192; i += 256) ((float*)acc)[i] = 0.f;
  if (t == 0) cnt = 0;
  __syncthreads();
  // bulk scan: 256 rows x 64 cols, all loads independent
  for (int cc = 0; cc < 16; ++cc) {
    int lin = cc * 256 + t;  // 0..4095
    int row = lin >> 4, c4 = lin & 15;
    float4 v = *(const float4*)(tm + (size_t)(row0 + row) * NI + col0 + (c4 << 2));
    int code = (row << 6) | (c4 << 2);
    if (v.x != 0.f) nz[atomicAdd(&cnt, 1)] = code;
    if (v.y != 0.f) nz[atomicAdd(&cnt, 1)] = code + 1;
    if (v.z != 0.f) nz[atomicAdd(&cnt, 1)] = code + 2;
    if (v.w != 0.f) nz[atomicAdd(&cnt, 1)] = code + 3;
  }
  __syncthreads();
  int n = min(cnt, 512);
  int half = t >> 7, e = t & 127;
  for (int p = half; p < n; p += 2) {
    int code = nz[p];
    int u = row0 + (code >> 6), c = code & 63;
    atomicAdd(&acc[c][e], uew[(size_t)u * 128 + e]);
  }
  __syncthreads();
  for (int i = t; i < 8192; i += 256)
    atomicAdd(&itemf[((size_t)col0 + (i >> 7)) * 128 + (i & 127)], ((float*)acc)[i]);
}

// ---------------------------------------------------------------------------
// K5: per (b,r): scan rel row, on-the-fly softmax over K per neighbor item,
// accumulate s_u and rel@tip; emit ubw-weighted tun and proj.
__global__ void k_user(const int* __restrict__ user, const float* __restrict__ relm,
                       const float* __restrict__ si, const float* __restrict__ tip,
                       const float* __restrict__ uemb, const float* __restrict__ WK,
                       const float* __restrict__ BK, const float* __restrict__ ibW,
                       const float* __restrict__ ubd, const float* __restrict__ mw,
                       float* __restrict__ wtun, float* __restrict__ proj) {
  int bid = blockIdx.x;
  int r = bid >> 9, b = bid & 511;
  int u = user[b];
  const float* rel = relm + ((size_t)r * NU + u) * NI;
  __shared__ int nz[512];
  __shared__ int cnt;
  __shared__ __align__(16) float uel[128];
  __shared__ float redA[4][128];
  __shared__ float redB[4][128];
  __shared__ float tu[128];
  int t = threadIdx.x;  // 256
  if (t == 0) cnt = 0;
  if (t < 32) ((float4*)uel)[t] = ((const float4*)(uemb + (size_t)u * 128))[t];
  __syncthreads();
  const float4* rel4 = (const float4*)rel;
#pragma unroll
  for (int c = 0; c < 4; ++c) {
    int idx4 = c * 256 + t;
    float4 v = rel4[idx4];
    int j0 = idx4 << 2;
    if (v.x != 0.f) nz[atomicAdd(&cnt, 1)] = j0;
    if (v.y != 0.f) nz[atomicAdd(&cnt, 1)] = j0 + 1;
    if (v.z != 0.f) nz[atomicAdd(&cnt, 1)] = j0 + 2;
    if (v.w != 0.f) nz[atomicAdd(&cnt, 1)] = j0 + 3;
  }
  __syncthreads();
  int n = min(cnt, 512);
  int wid = t >> 6, lane = t & 63;
  int k = lane >> 4;  // head: 16 lanes per head, float2 per lane covers D=32
  float2 myue = ((const float2*)uel)[lane];
  float sux = 0.f, suy = 0.f, tpx = 0.f, tpy = 0.f;
  const float2* si2 = (const float2*)si;
  const float2* tip2 = (const float2*)(tip + (size_t)r * NI * 128);
  for (int p = wid; p < n; p += 4) {
    int i = nz[p];
    float2 sv = si2[(size_t)i * 64 + lane];
    float lg = myue.x * sv.x + myue.y * sv.y;
    lg += __shfl_xor(lg, 1);
    lg += __shfl_xor(lg, 2);
    lg += __shfl_xor(lg, 4);
    lg += __shfl_xor(lg, 8);
    float l0 = __shfl(lg, 0), l1 = __shfl(lg, 16), l2 = __shfl(lg, 32), l3 = __shfl(lg, 48);
    float mx = fmaxf(fmaxf(l0, l1), fmaxf(l2, l3));
    float e0 = __expf(l0 - mx), e1 = __expf(l1 - mx), e2 = __expf(l2 - mx), e3 = __expf(l3 - mx);
    float inv = 1.f / (e0 + e1 + e2 + e3);
    float myr = (k == 0 ? e0 : k == 1 ? e1 : k == 2 ? e2 : e3) * inv;
    sux += myr * sv.x;
    suy += myr * sv.y;
    float2 tv = tip2[(size_t)i * 64 + lane];
    tpx += tv.x;
    tpy += tv.y;
  }
  redA[wid][2 * lane] = sux; redA[wid][2 * lane + 1] = suy;
  redB[wid][2 * lane] = tpx; redB[wid][2 * lane + 1] = tpy;
  __syncthreads();
  if (t < 128) {
    float suv = redA[0][t] + redA[1][t] + redA[2][t] + redA[3][t];
    float tipv = redB[0][t] + redB[1][t] + redB[2][t] + redB[3][t];
    float a = BK[t];
    const float4* wk4 = (const float4*)(WK + (size_t)t * 128);
    const float4* ue4 = (const float4*)uel;
#pragma unroll 8
    for (int c = 0; c < 32; ++c) {
      float4 w = wk4[c], v = ue4[c];
      a += w.x * v.x + w.y * v.y + w.z * v.z + w.w * v.w;
    }
    a = fmaxf(a, 0.f);
    float sq = a * a;
#pragma unroll
    for (int m = 1; m <= 16; m <<= 1) sq += __shfl_xor(sq, m);
    float su = a / fmaxf(sqrtf(sq), 1e-12f) + suv;
    float sq2 = su * su;
#pragma unroll
    for (int m = 1; m <= 16; m <<= 1) sq2 += __shfl_xor(sq2, m);
    float tun = su / fmaxf(sqrtf(sq2), 1e-12f);
    float d0 = ubd[u * 3], d1 = ubd[u * 3 + 1], d2 = ubd[u * 3 + 2];
    float w0 = mw[0], w1 = mw[1], w2 = mw[2];
    float tw = d0 * w0 + d1 * w1 + d2 * w2;
    float dr = (r == 0 ? d0 : r == 1 ? d1 : d2);
    float wr = (r == 0 ? w0 : r == 1 ? w1 : w2);
    wtun[(size_t)(b * 3 + r) * 128 + t] = (dr * wr / (tw + FEPS)) * tun;
    tu[t] = tipv / (dr + FEPS);
  }
  __syncthreads();
  int ep = t & 127, hh = t >> 7;
  const float* Wb = ibW + (size_t)r * 16384;
  float pacc = 0.f;
  for (int e = hh * 64; e < hh * 64 + 64; ++e) pacc += tu[e] * Wb[e * 128 + ep];
  redA[hh][ep] = pacc;
  __syncthreads();
  if (hh == 0) proj[(size_t)(b * 3 + r) * 128 + ep] = redA[0][ep] + redA[1][ep];
}

// ---------------------------------------------------------------------------
// K6: uf[b] = (sum_r wtun[b,r]) @ W ; per-b uf^2 partial
__global__ void k_uf(const float* __restrict__ wtun, const float* __restrict__ Wm,
                     float* __restrict__ uf, float* __restrict__ uf2p) {
  int b = blockIdx.x, t = threadIdx.x;  // 128
  __shared__ float comb[128];
  __shared__ float part[2];
  comb[t] = wtun[(size_t)(b * 3) * 128 + t] + wtun[(size_t)(b * 3 + 1) * 128 + t] +
            wtun[(size_t)(b * 3 + 2) * 128 + t];
  __syncthreads();
  float acc = 0.f;
  for (int e = 0; e < 128; ++e) acc += comb[e] * Wm[e * 128 + t];
  uf[(size_t)b * 128 + t] = acc;
  float sq = acc * acc;
#pragma unroll
  for (int m = 1; m <= 32; m <<= 1) sq += __shfl_xor(sq, m);
  if ((t & 63) == 0) part[t >> 6] = sq;
  __syncthreads();
  if (t == 0) uf2p[b] = part[0] + part[1];
}

// ---------------------------------------------------------------------------
// K7: one wave per (b,l): score1 + LAMB*score2/R ; itf^2 partial per block
__global__ void k_score(const int* __restrict__ item, const float* __restrict__ itemf,
                        const float* __restrict__ uf, const float* __restrict__ tip,
                        const float* __restrict__ proj, float* __restrict__ out,
                        float* __restrict__ itf2p) {
  int t = threadIdx.x, wid = t >> 6, lane = t & 63;
  int idx = blockIdx.x * 4 + wid;  // < 51200
  int b = idx / NL;
  int it = item[idx];
  float2 av = ((const float2*)(itemf + (size_t)it * 128))[lane];
  float2 cv = ((const float2*)(uf + (size_t)b * 128))[lane];
  float s1 = av.x * cv.x + av.y * cv.y;
  float sqi = av.x * av.x + av.y * av.y;
  float s2 = 0.f;
#pragma unroll
  for (int r = 0; r < 3; ++r) {
    float2 tv = ((const float2*)(tip + ((size_t)r * NI + it) * 128))[lane];
    float2 pv = ((const float2*)(proj + (size_t)(b * 3 + r) * 128))[lane];
    s2 += tv.x * pv.x + tv.y * pv.y;
  }
#pragma unroll
  for (int m = 1; m <= 32; m <<= 1) {
    s1 += __shfl_xor(s1, m);
    s2 += __shfl_xor(s2, m);
    sqi += __shfl_xor(sqi, m);
  }
  if (lane == 0) out[idx] = s1 + 0.5f * (s2 * (1.f / 3.f));
  __shared__ float sh[4];
  if (lane == 0) sh[wid] = sqi;
  __syncthreads();
  if (t == 0) itf2p[blockIdx.x] = sh[0] + sh[1] + sh[2] + sh[3];
}

// ---------------------------------------------------------------------------
// K8: L2_loss = 1e-4 * (100 * sum uf^2 + sum itf^2)
__global__ void k_final(const float* __restrict__ itf2p, const float* __restrict__ uf2p,
                        float* __restrict__ out) {
  int t = threadIdx.x;  // 256
  float v = 0.f;
  for (int i = t; i < 12800; i += 256) v += itf2p[i];
  float vu = 0.f;
  for (int i = t; i < NB; i += 256) vu += uf2p[i];
  v += 100.f * vu;
#pragma unroll
  for (int m = 1; m <= 32; m <<= 1) v += __shfl_xor(v, m);
  __shared__ float sh[4];
  if ((t & 63) == 0) sh[t >> 6] = v;
  __syncthreads();
  if (t == 0) out[NB * NL] = 1e-4f * (sh[0] + sh[1] + sh[2] + sh[3]);
}

// ---------------------------------------------------------------------------
extern "C" void kernel_launch(void* const* d_in, const int* in_sizes, int n_in,
                              void* d_out, int out_size, void* d_ws, size_t ws_size,
                              hipStream_t stream) {
  (void)in_sizes; (void)n_in; (void)out_size; (void)ws_size;
  const int* user = (const int*)d_in[0];
  const int* item = (const int*)d_in[1];
  const float* uemb = (const float*)d_in[2];
  const float* iemb = (const float*)d_in[3];
  const float* mw = (const float*)d_in[4];
  const float* ibW = (const float*)d_in[5];
  const float* ipW = (const float*)d_in[6];
  const float* Wm = (const float*)d_in[7];
  const float* WK = (const float*)d_in[8];
  const float* BK = (const float*)d_in[9];
  const float* tm = (const float*)d_in[10];
  const float* relm = (const float*)d_in[11];
  const float* ig = (const float*)d_in[12];
  const float* igd = (const float*)d_in[13];
  const float* ubd = (const float*)d_in[14];
  float* out = (float*)d_out;
  float* ws = (float*)d_ws;

  hipMemsetAsync(ws + WS_ITEMF, 0, (size_t)NI * 128 * sizeof(float), stream);
  k_si<<<NI, 128, 0, stream>>>(iemb, WK, BK, ws + WS_SI);
  k_agg<<<NR * NI, 256, 0, stream>>>(ig, iemb, igd, ws + WS_AGG);
  k_bmm<<<1024, 256, 0, stream>>>(ws + WS_AGG, ipW, uemb, Wm, ws + WS_TIP, ws + WS_UEW);
  k_preitemf<<<1024, 256, 0, stream>>>(tm, ws + WS_UEW, ws + WS_ITEMF);
  k_user<<<NR * NB, 256, 0, stream>>>(user, relm, ws + WS_SI, ws + WS_TIP, uemb, WK, BK,
                                      ibW, ubd, mw, ws + WS_WTUN, ws + WS_PROJ);
  k_uf<<<NB, 128, 0, stream>>>(ws + WS_WTUN, Wm, ws + WS_UF, ws + WS_UF2P);
  k_score<<<12800, 256, 0, stream>>>(item, ws + WS_ITEMF, ws + WS_UF, ws + WS_TIP,
                                     ws + WS_PROJ, out, ws + WS_ITF2P);
  k_final<<<1, 256, 0, stream>>>(ws + WS_ITF2P, ws + WS_UF2P, out);
}

// Round 3
// 198.964 us; speedup vs baseline: 1.7268x; 1.5462x over previous
//
#include <hip/hip_runtime.h>

#define NU 4096
#define NI 4096
#define NR 3
#define NB 512
#define NL 100
#define FEPS 1e-8f

// workspace layout (float offsets)
#define WS_SI    0            // [NI*128]   s_i: [i][k*32+d]
#define WS_AGG   524288       // [3*NI*128] graph-aggregated item emb per relation
#define WS_TIP   2097152      // [3*NI*128] tip per relation
#define WS_UEW   3670016      // [NU*128]   user_embedding @ W
#define WS_ITEMF 4194304      // [NI*128]   item_feature
#define WS_WTUN  4718592      // [NB*3*128] ubw-weighted tun per (b,r)
#define WS_PROJ  4915200      // [NB*3*128] proj per (b,r)
#define WS_UF    5111808      // [NB*128]   uf_sel
#define WS_UF2P  5177344      // [NB]       per-b uf^2 partials
#define WS_ITF2P 5177856      // [12800]    per-block itf^2 partials
#define WS_BMT   5190656      // [4096*64 ulong = 2MB] transposed bitmask of tm

// ---------------------------------------------------------------------------
// K1: s_i[i][t] = l2norm_D(relu(W_K @ item_emb[i] + B_K)), t = k*32+d
__global__ void k_si(const float* __restrict__ iemb, const float* __restrict__ WK,
                     const float* __restrict__ BK, float* __restrict__ si) {
  int i = blockIdx.x;
  __shared__ __align__(16) float embs[128];
  int t = threadIdx.x;  // 128
  if (t < 32) ((float4*)embs)[t] = ((const float4*)(iemb + (size_t)i * 128))[t];
  __syncthreads();
  float acc = BK[t];
  const float4* wk4 = (const float4*)(WK + (size_t)t * 128);
  const float4* e4 = (const float4*)embs;
#pragma unroll 8
  for (int c = 0; c < 32; ++c) {
    float4 w = wk4[c], v = e4[c];
    acc += w.x * v.x + w.y * v.y + w.z * v.z + w.w * v.w;
  }
  acc = fmaxf(acc, 0.f);
  float sq = acc * acc;
#pragma unroll
  for (int m = 1; m <= 16; m <<= 1) sq += __shfl_xor(sq, m);
  si[(size_t)i * 128 + t] = acc / fmaxf(sqrtf(sq), 1e-12f);
}

// ---------------------------------------------------------------------------
// K2: agg[r][i] = (item_graphs[r][i,:] @ item_emb) / (deg+eps)   (pure scan)
__global__ void k_agg(const float* __restrict__ G, const float* __restrict__ emb,
                      const float* __restrict__ deg, float* __restrict__ agg) {
  int bid = blockIdx.x;  // r*4096 + i
  const float4* row4 = (const float4*)(G + (size_t)bid * NI);
  __shared__ int nz[512];
  __shared__ int cnt;
  __shared__ float4 red[8][32];
  int t = threadIdx.x;  // 256
  if (t == 0) cnt = 0;
  __syncthreads();
#pragma unroll
  for (int c = 0; c < 4; ++c) {
    int idx4 = c * 256 + t;
    float4 v = row4[idx4];
    int j0 = idx4 << 2;
    if (v.x != 0.f) nz[atomicAdd(&cnt, 1)] = j0;
    if (v.y != 0.f) nz[atomicAdd(&cnt, 1)] = j0 + 1;
    if (v.z != 0.f) nz[atomicAdd(&cnt, 1)] = j0 + 2;
    if (v.w != 0.f) nz[atomicAdd(&cnt, 1)] = j0 + 3;
  }
  __syncthreads();
  int n = min(cnt, 512);
  int g = t >> 5, f = t & 31;  // 8 neighbor-slots x 32 lanes (float4 each)
  float4 acc = {0.f, 0.f, 0.f, 0.f};
  const float4* emb4 = (const float4*)emb;
  for (int p = g; p < n; p += 8) {
    float4 v = emb4[(size_t)nz[p] * 32 + f];
    acc.x += v.x; acc.y += v.y; acc.z += v.z; acc.w += v.w;
  }
  red[g][f] = acc;
  __syncthreads();
  if (t < 32) {
    float4 s = red[0][t];
#pragma unroll
    for (int q = 1; q < 8; ++q) {
      float4 v = red[q][t];
      s.x += v.x; s.y += v.y; s.z += v.z; s.w += v.w;
    }
    float inv = 1.f / (deg[bid] + FEPS);
    s.x *= inv; s.y *= inv; s.z *= inv; s.w *= inv;
    ((float4*)(agg + (size_t)bid * 128))[t] = s;
  }
}

// ---------------------------------------------------------------------------
// K3: batched dense [4096,128]@[128,128]: batches 0-2 tip=agg@ipW[r], batch 3 uew=uemb@W
__global__ void k_bmm(const float* __restrict__ agg, const float* __restrict__ ipW,
                      const float* __restrict__ uemb, const float* __restrict__ Wm,
                      float* __restrict__ tip, float* __restrict__ uew) {
  int batch = blockIdx.x >> 8, rb = blockIdx.x & 255;  // 16 rows per block
  const float* in;
  const float* Wp;
  float* out;
  if (batch < 3) {
    in = agg + (size_t)batch * NI * 128;
    Wp = ipW + (size_t)batch * 16384;
    out = tip + (size_t)batch * NI * 128;
  } else {
    in = uemb; Wp = Wm; out = uew;
  }
  __shared__ __align__(16) float inl[16][128];
  int t = threadIdx.x;  // 256
  const float4* in4 = (const float4*)(in + (size_t)rb * 2048);
  for (int c = t; c < 512; c += 256) ((float4*)inl)[c] = in4[c];
  __syncthreads();
  int c = t & 127, g = t >> 7;
  float acc[8];
#pragma unroll
  for (int rr = 0; rr < 8; ++rr) acc[rr] = 0.f;
  for (int e = 0; e < 128; ++e) {
    float wv = Wp[e * 128 + c];
#pragma unroll
    for (int rr = 0; rr < 8; ++rr) acc[rr] += inl[g * 8 + rr][e] * wv;
  }
#pragma unroll
  for (int rr = 0; rr < 8; ++rr) out[((size_t)rb * 16 + g * 8 + rr) * 128 + c] = acc[rr];
}

// ---------------------------------------------------------------------------
// K4a: bmT[ct][row] = 64-bit mask of tm[row][64*ct .. 64*ct+63]  (coalesced stream)
__global__ void k_bits(const float* __restrict__ tm, unsigned long long* __restrict__ bmT) {
  int row = blockIdx.x;
  int t = threadIdx.x;  // 256
  __shared__ unsigned short sh[256];
  const float4* r4 = (const float4*)(tm + (size_t)row * NI);
  unsigned int m = 0;
#pragma unroll
  for (int q = 0; q < 4; ++q) {
    float4 v = r4[t * 4 + q];
    int b = q * 4;
    if (v.x != 0.f) m |= (1u << b);
    if (v.y != 0.f) m |= (1u << (b + 1));
    if (v.z != 0.f) m |= (1u << (b + 2));
    if (v.w != 0.f) m |= (1u << (b + 3));
  }
  sh[t] = (unsigned short)m;
  __syncthreads();
  if (t < 64) {
    unsigned long long mm = (unsigned long long)sh[4 * t]
      | ((unsigned long long)sh[4 * t + 1] << 16)
      | ((unsigned long long)sh[4 * t + 2] << 32)
      | ((unsigned long long)sh[4 * t + 3] << 48);
    bmT[(size_t)t * NU + row] = mm;
  }
}

// ---------------------------------------------------------------------------
// K4b: itemf[i] = sum_{u: tm[u][i]!=0} uew[u]   (CSC via bitmask, no atomics to global)
__global__ void k_itemf_csc(const unsigned long long* __restrict__ bmT,
                            const float* __restrict__ uew, float* __restrict__ itemf) {
  int i = blockIdx.x;  // item
  int ct = i >> 6;
  unsigned long long bitm = 1ull << (i & 63);
  __shared__ int lst[192];
  __shared__ int cnt;
  __shared__ float red[3][128];
  int t = threadIdx.x;  // 256
  if (t == 0) cnt = 0;
  __syncthreads();
  const unsigned long long* col = bmT + (size_t)ct * NU;
#pragma unroll
  for (int cc = 0; cc < 16; ++cc) {
    unsigned long long m = col[cc * 256 + t];
    if (m & bitm) lst[atomicAdd(&cnt, 1)] = cc * 256 + t;
  }
  __syncthreads();
  int n = min(cnt, 192);
  int w = t >> 6, l = t & 63;
  float ax = 0.f, ay = 0.f;
  const float2* uew2 = (const float2*)uew;
  for (int p = w; p < n; p += 4) {
    float2 v = uew2[(size_t)lst[p] * 64 + l];
    ax += v.x; ay += v.y;
  }
  if (w > 0) { red[w - 1][2 * l] = ax; red[w - 1][2 * l + 1] = ay; }
  __syncthreads();
  if (w == 0) {
    float2 o;
    o.x = ax + red[0][2 * l] + red[1][2 * l] + red[2][2 * l];
    o.y = ay + red[0][2 * l + 1] + red[1][2 * l + 1] + red[2][2 * l + 1];
    ((float2*)(itemf + (size_t)i * 128))[l] = o;
  }
}

// ---------------------------------------------------------------------------
// K5: per (b,r): scan rel row, on-the-fly softmax over K per neighbor item,
// accumulate s_u and rel@tip; emit ubw-weighted tun and proj.
__global__ void k_user(const int* __restrict__ user, const float* __restrict__ relm,
                       const float* __restrict__ si, const float* __restrict__ tip,
                       const float* __restrict__ uemb, const float* __restrict__ WK,
                       const float* __restrict__ BK, const float* __restrict__ ibW,
                       const float* __restrict__ ubd, const float* __restrict__ mw,
                       float* __restrict__ wtun, float* __restrict__ proj) {
  int bid = blockIdx.x;
  int r = bid >> 9, b = bid & 511;
  int u = user[b];
  const float* rel = relm + ((size_t)r * NU + u) * NI;
  __shared__ int nz[512];
  __shared__ int cnt;
  __shared__ __align__(16) float uel[128];
  __shared__ float redA[4][128];
  __shared__ float redB[4][128];
  __shared__ float tu[128];
  int t = threadIdx.x;  // 256
  if (t == 0) cnt = 0;
  if (t < 32) ((float4*)uel)[t] = ((const float4*)(uemb + (size_t)u * 128))[t];
  __syncthreads();
  const float4* rel4 = (const float4*)rel;
#pragma unroll
  for (int c = 0; c < 4; ++c) {
    int idx4 = c * 256 + t;
    float4 v = rel4[idx4];
    int j0 = idx4 << 2;
    if (v.x != 0.f) nz[atomicAdd(&cnt, 1)] = j0;
    if (v.y != 0.f) nz[atomicAdd(&cnt, 1)] = j0 + 1;
    if (v.z != 0.f) nz[atomicAdd(&cnt, 1)] = j0 + 2;
    if (v.w != 0.f) nz[atomicAdd(&cnt, 1)] = j0 + 3;
  }
  __syncthreads();
  int n = min(cnt, 512);
  int wid = t >> 6, lane = t & 63;
  int k = lane >> 4;  // head: 16 lanes per head, float2 per lane covers D=32
  float2 myue = ((const float2*)uel)[lane];
  float sux = 0.f, suy = 0.f, tpx = 0.f, tpy = 0.f;
  const float2* si2 = (const float2*)si;
  const float2* tip2 = (const float2*)(tip + (size_t)r * NI * 128);
  for (int p = wid; p < n; p += 4) {
    int i = nz[p];
    float2 sv = si2[(size_t)i * 64 + lane];
    float lg = myue.x * sv.x + myue.y * sv.y;
    lg += __shfl_xor(lg, 1);
    lg += __shfl_xor(lg, 2);
    lg += __shfl_xor(lg, 4);
    lg += __shfl_xor(lg, 8);
    float l0 = __shfl(lg, 0), l1 = __shfl(lg, 16), l2 = __shfl(lg, 32), l3 = __shfl(lg, 48);
    float mx = fmaxf(fmaxf(l0, l1), fmaxf(l2, l3));
    float e0 = __expf(l0 - mx), e1 = __expf(l1 - mx), e2 = __expf(l2 - mx), e3 = __expf(l3 - mx);
    float inv = 1.f / (e0 + e1 + e2 + e3);
    float myr = (k == 0 ? e0 : k == 1 ? e1 : k == 2 ? e2 : e3) * inv;
    sux += myr * sv.x;
    suy += myr * sv.y;
    float2 tv = tip2[(size_t)i * 64 + lane];
    tpx += tv.x;
    tpy += tv.y;
  }
  redA[wid][2 * lane] = sux; redA[wid][2 * lane + 1] = suy;
  redB[wid][2 * lane] = tpx; redB[wid][2 * lane + 1] = tpy;
  __syncthreads();
  if (t < 128) {
    float suv = redA[0][t] + redA[1][t] + redA[2][t] + redA[3][t];
    float tipv = redB[0][t] + redB[1][t] + redB[2][t] + redB[3][t];
    float a = BK[t];
    const float4* wk4 = (const float4*)(WK + (size_t)t * 128);
    const float4* ue4 = (const float4*)uel;
#pragma unroll 8
    for (int c = 0; c < 32; ++c) {
      float4 w = wk4[c], v = ue4[c];
      a += w.x * v.x + w.y * v.y + w.z * v.z + w.w * v.w;
    }
    a = fmaxf(a, 0.f);
    float sq = a * a;
#pragma unroll
    for (int m = 1; m <= 16; m <<= 1) sq += __shfl_xor(sq, m);
    float su = a / fmaxf(sqrtf(sq), 1e-12f) + suv;
    float sq2 = su * su;
#pragma unroll
    for (int m = 1; m <= 16; m <<= 1) sq2 += __shfl_xor(sq2, m);
    float tun = su / fmaxf(sqrtf(sq2), 1e-12f);
    float d0 = ubd[u * 3], d1 = ubd[u * 3 + 1], d2 = ubd[u * 3 + 2];
    float w0 = mw[0], w1 = mw[1], w2 = mw[2];
    float tw = d0 * w0 + d1 * w1 + d2 * w2;
    float dr = (r == 0 ? d0 : r == 1 ? d1 : d2);
    float wr = (r == 0 ? w0 : r == 1 ? w1 : w2);
    wtun[(size_t)(b * 3 + r) * 128 + t] = (dr * wr / (tw + FEPS)) * tun;
    tu[t] = tipv / (dr + FEPS);
  }
  __syncthreads();
  int ep = t & 127, hh = t >> 7;
  const float* Wb = ibW + (size_t)r * 16384;
  float pacc = 0.f;
  for (int e = hh * 64; e < hh * 64 + 64; ++e) pacc += tu[e] * Wb[e * 128 + ep];
  redA[hh][ep] = pacc;
  __syncthreads();
  if (hh == 0) proj[(size_t)(b * 3 + r) * 128 + ep] = redA[0][ep] + redA[1][ep];
}

// ---------------------------------------------------------------------------
// K6: uf[b] = (sum_r wtun[b,r]) @ W ; per-b uf^2 partial
__global__ void k_uf(const float* __restrict__ wtun, const float* __restrict__ Wm,
                     float* __restrict__ uf, float* __restrict__ uf2p) {
  int b = blockIdx.x, t = threadIdx.x;  // 128
  __shared__ float comb[128];
  __shared__ float part[2];
  comb[t] = wtun[(size_t)(b * 3) * 128 + t] + wtun[(size_t)(b * 3 + 1) * 128 + t] +
            wtun[(size_t)(b * 3 + 2) * 128 + t];
  __syncthreads();
  float acc = 0.f;
  for (int e = 0; e < 128; ++e) acc += comb[e] * Wm[e * 128 + t];
  uf[(size_t)b * 128 + t] = acc;
  float sq = acc * acc;
#pragma unroll
  for (int m = 1; m <= 32; m <<= 1) sq += __shfl_xor(sq, m);
  if ((t & 63) == 0) part[t >> 6] = sq;
  __syncthreads();
  if (t == 0) uf2p[b] = part[0] + part[1];
}

// ---------------------------------------------------------------------------
// K7: one wave per (b,l): score1 + LAMB*score2/R ; itf^2 partial per block
__global__ void k_score(const int* __restrict__ item, const float* __restrict__ itemf,
                        const float* __restrict__ uf, const float* __restrict__ tip,
                        const float* __restrict__ proj, float* __restrict__ out,
                        float* __restrict__ itf2p) {
  int t = threadIdx.x, wid = t >> 6, lane = t & 63;
  int idx = blockIdx.x * 4 + wid;  // < 51200
  int b = idx / NL;
  int it = item[idx];
  float2 av = ((const float2*)(itemf + (size_t)it * 128))[lane];
  float2 cv = ((const float2*)(uf + (size_t)b * 128))[lane];
  float s1 = av.x * cv.x + av.y * cv.y;
  float sqi = av.x * av.x + av.y * av.y;
  float s2 = 0.f;
#pragma unroll
  for (int r = 0; r < 3; ++r) {
    float2 tv = ((const float2*)(tip + ((size_t)r * NI + it) * 128))[lane];
    float2 pv = ((const float2*)(proj + (size_t)(b * 3 + r) * 128))[lane];
    s2 += tv.x * pv.x + tv.y * pv.y;
  }
#pragma unroll
  for (int m = 1; m <= 32; m <<= 1) {
    s1 += __shfl_xor(s1, m);
    s2 += __shfl_xor(s2, m);
    sqi += __shfl_xor(sqi, m);
  }
  if (lane == 0) out[idx] = s1 + 0.5f * (s2 * (1.f / 3.f));
  __shared__ float sh[4];
  if (lane == 0) sh[wid] = sqi;
  __syncthreads();
  if (t == 0) itf2p[blockIdx.x] = sh[0] + sh[1] + sh[2] + sh[3];
}

// ---------------------------------------------------------------------------
// K8: L2_loss = 1e-4 * (100 * sum uf^2 + sum itf^2)
__global__ void k_final(const float* __restrict__ itf2p, const float* __restrict__ uf2p,
                        float* __restrict__ out) {
  int t = threadIdx.x;  // 256
  float v = 0.f;
  for (int i = t; i < 12800; i += 256) v += itf2p[i];
  float vu = 0.f;
  for (int i = t; i < NB; i += 256) vu += uf2p[i];
  v += 100.f * vu;
#pragma unroll
  for (int m = 1; m <= 32; m <<= 1) v += __shfl_xor(v, m);
  __shared__ float sh[4];
  if ((t & 63) == 0) sh[t >> 6] = v;
  __syncthreads();
  if (t == 0) out[NB * NL] = 1e-4f * (sh[0] + sh[1] + sh[2] + sh[3]);
}

// ---------------------------------------------------------------------------
extern "C" void kernel_launch(void* const* d_in, const int* in_sizes, int n_in,
                              void* d_out, int out_size, void* d_ws, size_t ws_size,
                              hipStream_t stream) {
  (void)in_sizes; (void)n_in; (void)out_size; (void)ws_size;
  const int* user = (const int*)d_in[0];
  const int* item = (const int*)d_in[1];
  const float* uemb = (const float*)d_in[2];
  const float* iemb = (const float*)d_in[3];
  const float* mw = (const float*)d_in[4];
  const float* ibW = (const float*)d_in[5];
  const float* ipW = (const float*)d_in[6];
  const float* Wm = (const float*)d_in[7];
  const float* WK = (const float*)d_in[8];
  const float* BK = (const float*)d_in[9];
  const float* tm = (const float*)d_in[10];
  const float* relm = (const float*)d_in[11];
  const float* ig = (const float*)d_in[12];
  const float* igd = (const float*)d_in[13];
  const float* ubd = (const float*)d_in[14];
  float* out = (float*)d_out;
  float* ws = (float*)d_ws;
  unsigned long long* bmT = (unsigned long long*)(ws + WS_BMT);

  k_si<<<NI, 128, 0, stream>>>(iemb, WK, BK, ws + WS_SI);
  k_bits<<<NU, 256, 0, stream>>>(tm, bmT);
  k_agg<<<NR * NI, 256, 0, stream>>>(ig, iemb, igd, ws + WS_AGG);
  k_bmm<<<1024, 256, 0, stream>>>(ws + WS_AGG, ipW, uemb, Wm, ws + WS_TIP, ws + WS_UEW);
  k_itemf_csc<<<NI, 256, 0, stream>>>(bmT, ws + WS_UEW, ws + WS_ITEMF);
  k_user<<<NR * NB, 256, 0, stream>>>(user, relm, ws + WS_SI, ws + WS_TIP, uemb, WK, BK,
                                      ibW, ubd, mw, ws + WS_WTUN, ws + WS_PROJ);
  k_uf<<<NB, 128, 0, stream>>>(ws + WS_WTUN, Wm, ws + WS_UF, ws + WS_UF2P);
  k_score<<<12800, 256, 0, stream>>>(item, ws + WS_ITEMF, ws + WS_UF, ws + WS_TIP,
                                     ws + WS_PROJ, out, ws + WS_ITF2P);
  k_final<<<1, 256, 0, stream>>>(ws + WS_ITF2P, ws + WS_UF2P, out);
}

// Round 4
// 186.602 us; speedup vs baseline: 1.8411x; 1.0662x over previous
//
#include <hip/hip_runtime.h>

#define NU 4096
#define NI 4096
#define NR 3
#define NB 512
#define NL 100
#define FEPS 1e-8f

// workspace layout (float offsets)
#define WS_SI    0            // [NI*128]   s_i: [i][k*32+d]
#define WS_EMBW  524288       // [3*NI*128] iemb @ ipW[r]
#define WS_TIP   2097152      // [3*NI*128] tip per relation
#define WS_UEW   3670016      // [NU*128]   user_embedding @ W
#define WS_ITEMF 4194304      // [NI*128]   item_feature
#define WS_WTUN  4718592      // [NB*3*128] ubw-weighted tun per (b,r)
#define WS_PROJ  4915200      // [NB*3*128] proj per (b,r)
#define WS_UF    5111808      // [NB*128]   uf_sel
#define WS_UF2P  5177344      // [NB]       per-b uf^2 partials
#define WS_ITF2P 5177856      // [12800]    per-block itf^2 partials
#define WS_BMT   5190656      // [4096*64 ulong = 2MB] transposed bitmask of tm

// ---------------------------------------------------------------------------
// K1: fused batched GEMM + s_i projection.
// bid<1024: batch GEMM [4096,128]@[128,128]: b0-2 embW[r]=iemb@ipW[r], b3 uew=uemb@W
// bid>=1024 (2048 blocks): s_i for 2 items per block
__global__ void k_bmm_si(const float* __restrict__ iemb, const float* __restrict__ ipW,
                         const float* __restrict__ uemb, const float* __restrict__ Wm,
                         const float* __restrict__ WK, const float* __restrict__ BK,
                         float* __restrict__ embW, float* __restrict__ uew,
                         float* __restrict__ si) {
  __shared__ __align__(16) float shbuf[2048];
  int t = threadIdx.x;  // 256
  int bid = blockIdx.x;
  if (bid < 1024) {
    int batch = bid >> 8, rb = bid & 255;  // 16 rows per block
    const float* in;
    const float* Wp;
    float* out;
    if (batch < 3) {
      in = iemb;
      Wp = ipW + (size_t)batch * 16384;
      out = embW + (size_t)batch * NI * 128;
    } else {
      in = uemb; Wp = Wm; out = uew;
    }
    const float4* in4 = (const float4*)(in + (size_t)rb * 2048);
    for (int c = t; c < 512; c += 256) ((float4*)shbuf)[c] = in4[c];
    __syncthreads();
    int c = t & 127, g = t >> 7;
    float acc[8];
#pragma unroll
    for (int rr = 0; rr < 8; ++rr) acc[rr] = 0.f;
    for (int e = 0; e < 128; ++e) {
      float wv = Wp[e * 128 + c];
#pragma unroll
      for (int rr = 0; rr < 8; ++rr) acc[rr] += shbuf[(g * 8 + rr) * 128 + e] * wv;
    }
#pragma unroll
    for (int rr = 0; rr < 8; ++rr) out[((size_t)rb * 16 + g * 8 + rr) * 128 + c] = acc[rr];
  } else {
    int tl = t & 127, half = t >> 7;
    int item = (bid - 1024) * 2 + half;
    float* embs = shbuf + half * 128;
    if (tl < 32) ((float4*)embs)[tl] = ((const float4*)(iemb + (size_t)item * 128))[tl];
    __syncthreads();
    float acc = BK[tl];
    const float4* wk4 = (const float4*)(WK + (size_t)tl * 128);
    const float4* e4 = (const float4*)embs;
#pragma unroll 8
    for (int c = 0; c < 32; ++c) {
      float4 w = wk4[c], v = e4[c];
      acc += w.x * v.x + w.y * v.y + w.z * v.z + w.w * v.w;
    }
    acc = fmaxf(acc, 0.f);
    float sq = acc * acc;
#pragma unroll
    for (int m = 1; m <= 16; m <<= 1) sq += __shfl_xor(sq, m);
    si[(size_t)item * 128 + tl] = acc / fmaxf(sqrtf(sq), 1e-12f);
  }
}

// ---------------------------------------------------------------------------
// K2: mega-scan. bid<4096: tm row -> bmT bits (interleaved coalesced).
// bid>=4096: graph row (r,i): nz scan -> gather embW[r] -> tip[r][i] directly.
__global__ void k_scan(const float* __restrict__ tm, const float* __restrict__ G,
                       const float* __restrict__ deg, const float* __restrict__ embW,
                       unsigned long long* __restrict__ bmT, float* __restrict__ tip) {
  int bid = blockIdx.x;
  int t = threadIdx.x;  // 256
  if (bid < NU) {
    __shared__ unsigned char nib[4][256];
    const float4* r4 = (const float4*)(tm + (size_t)bid * NI);
#pragma unroll
    for (int q = 0; q < 4; ++q) {
      float4 v = r4[q * 256 + t];
      unsigned m = 0;
      if (v.x != 0.f) m |= 1u;
      if (v.y != 0.f) m |= 2u;
      if (v.z != 0.f) m |= 4u;
      if (v.w != 0.f) m |= 8u;
      nib[q][t] = (unsigned char)m;
    }
    __syncthreads();
    if (t < 64) {
      unsigned long long mm = 0;
#pragma unroll
      for (int j = 0; j < 16; ++j) {
        int e = t * 16 + j;
        mm |= (unsigned long long)nib[e >> 8][e & 255] << (4 * j);
      }
      bmT[(size_t)t * NU + bid] = mm;
    }
  } else {
    int gid = bid - NU;  // r*4096 + i
    int r = gid >> 12;
    const float4* row4 = (const float4*)(G + (size_t)gid * NI);
    __shared__ int nz[512];
    __shared__ int cnt;
    __shared__ float4 red[8][32];
    if (t == 0) cnt = 0;
    __syncthreads();
#pragma unroll
    for (int c = 0; c < 4; ++c) {
      int idx4 = c * 256 + t;
      float4 v = row4[idx4];
      int j0 = idx4 << 2;
      if (v.x != 0.f) nz[atomicAdd(&cnt, 1)] = j0;
      if (v.y != 0.f) nz[atomicAdd(&cnt, 1)] = j0 + 1;
      if (v.z != 0.f) nz[atomicAdd(&cnt, 1)] = j0 + 2;
      if (v.w != 0.f) nz[atomicAdd(&cnt, 1)] = j0 + 3;
    }
    __syncthreads();
    int n = min(cnt, 512);
    int g = t >> 5, f = t & 31;  // 8 neighbor-slots x 32 lanes (float4 each)
    float4 acc = {0.f, 0.f, 0.f, 0.f};
    const float4* e4 = (const float4*)(embW + (size_t)r * NI * 128);
    for (int p = g; p < n; p += 8) {
      float4 v = e4[(size_t)nz[p] * 32 + f];
      acc.x += v.x; acc.y += v.y; acc.z += v.z; acc.w += v.w;
    }
    red[g][f] = acc;
    __syncthreads();
    if (t < 32) {
      float4 s = red[0][t];
#pragma unroll
      for (int q = 1; q < 8; ++q) {
        float4 v = red[q][t];
        s.x += v.x; s.y += v.y; s.z += v.z; s.w += v.w;
      }
      float inv = 1.f / (deg[gid] + FEPS);
      s.x *= inv; s.y *= inv; s.z *= inv; s.w *= inv;
      ((float4*)(tip + (size_t)gid * 128))[t] = s;
    }
  }
}

// ---------------------------------------------------------------------------
// K3: itemf[i] = sum_{u: tm[u][i]!=0} uew[u]   (CSC via bitmask, no atomics)
__global__ void k_itemf_csc(const unsigned long long* __restrict__ bmT,
                            const float* __restrict__ uew, float* __restrict__ itemf) {
  int i = blockIdx.x;  // item
  int ct = i >> 6;
  unsigned long long bitm = 1ull << (i & 63);
  __shared__ int lst[192];
  __shared__ int cnt;
  __shared__ float red[3][128];
  int t = threadIdx.x;  // 256
  if (t == 0) cnt = 0;
  __syncthreads();
  const unsigned long long* col = bmT + (size_t)ct * NU;
#pragma unroll
  for (int cc = 0; cc < 16; ++cc) {
    unsigned long long m = col[cc * 256 + t];
    if (m & bitm) lst[atomicAdd(&cnt, 1)] = cc * 256 + t;
  }
  __syncthreads();
  int n = min(cnt, 192);
  int w = t >> 6, l = t & 63;
  float ax = 0.f, ay = 0.f;
  const float2* uew2 = (const float2*)uew;
  for (int p = w; p < n; p += 4) {
    float2 v = uew2[(size_t)lst[p] * 64 + l];
    ax += v.x; ay += v.y;
  }
  if (w > 0) { red[w - 1][2 * l] = ax; red[w - 1][2 * l + 1] = ay; }
  __syncthreads();
  if (w == 0) {
    float2 o;
    o.x = ax + red[0][2 * l] + red[1][2 * l] + red[2][2 * l];
    o.y = ay + red[0][2 * l + 1] + red[1][2 * l + 1] + red[2][2 * l + 1];
    ((float2*)(itemf + (size_t)i * 128))[l] = o;
  }
}

// ---------------------------------------------------------------------------
// K4: per (b,r): scan rel row, on-the-fly softmax over K per neighbor item,
// accumulate s_u and rel@tip; emit ubw-weighted tun and proj.
__global__ void k_user(const int* __restrict__ user, const float* __restrict__ relm,
                       const float* __restrict__ si, const float* __restrict__ tip,
                       const float* __restrict__ uemb, const float* __restrict__ WK,
                       const float* __restrict__ BK, const float* __restrict__ ibW,
                       const float* __restrict__ ubd, const float* __restrict__ mw,
                       float* __restrict__ wtun, float* __restrict__ proj) {
  int bid = blockIdx.x;
  int r = bid >> 9, b = bid & 511;
  int u = user[b];
  const float* rel = relm + ((size_t)r * NU + u) * NI;
  __shared__ int nz[512];
  __shared__ int cnt;
  __shared__ __align__(16) float uel[128];
  __shared__ float redA[4][128];
  __shared__ float redB[4][128];
  __shared__ float tu[128];
  int t = threadIdx.x;  // 256
  if (t == 0) cnt = 0;
  if (t < 32) ((float4*)uel)[t] = ((const float4*)(uemb + (size_t)u * 128))[t];
  __syncthreads();
  const float4* rel4 = (const float4*)rel;
#pragma unroll
  for (int c = 0; c < 4; ++c) {
    int idx4 = c * 256 + t;
    float4 v = rel4[idx4];
    int j0 = idx4 << 2;
    if (v.x != 0.f) nz[atomicAdd(&cnt, 1)] = j0;
    if (v.y != 0.f) nz[atomicAdd(&cnt, 1)] = j0 + 1;
    if (v.z != 0.f) nz[atomicAdd(&cnt, 1)] = j0 + 2;
    if (v.w != 0.f) nz[atomicAdd(&cnt, 1)] = j0 + 3;
  }
  __syncthreads();
  int n = min(cnt, 512);
  int wid = t >> 6, lane = t & 63;
  int k = lane >> 4;  // head: 16 lanes per head, float2 per lane covers D=32
  float2 myue = ((const float2*)uel)[lane];
  float sux = 0.f, suy = 0.f, tpx = 0.f, tpy = 0.f;
  const float2* si2 = (const float2*)si;
  const float2* tip2 = (const float2*)(tip + (size_t)r * NI * 128);
  for (int p = wid; p < n; p += 4) {
    int i = nz[p];
    float2 sv = si2[(size_t)i * 64 + lane];
    float lg = myue.x * sv.x + myue.y * sv.y;
    lg += __shfl_xor(lg, 1);
    lg += __shfl_xor(lg, 2);
    lg += __shfl_xor(lg, 4);
    lg += __shfl_xor(lg, 8);
    float l0 = __shfl(lg, 0), l1 = __shfl(lg, 16), l2 = __shfl(lg, 32), l3 = __shfl(lg, 48);
    float mx = fmaxf(fmaxf(l0, l1), fmaxf(l2, l3));
    float e0 = __expf(l0 - mx), e1 = __expf(l1 - mx), e2 = __expf(l2 - mx), e3 = __expf(l3 - mx);
    float inv = 1.f / (e0 + e1 + e2 + e3);
    float myr = (k == 0 ? e0 : k == 1 ? e1 : k == 2 ? e2 : e3) * inv;
    sux += myr * sv.x;
    suy += myr * sv.y;
    float2 tv = tip2[(size_t)i * 64 + lane];
    tpx += tv.x;
    tpy += tv.y;
  }
  redA[wid][2 * lane] = sux; redA[wid][2 * lane + 1] = suy;
  redB[wid][2 * lane] = tpx; redB[wid][2 * lane + 1] = tpy;
  __syncthreads();
  if (t < 128) {
    float suv = redA[0][t] + redA[1][t] + redA[2][t] + redA[3][t];
    float tipv = redB[0][t] + redB[1][t] + redB[2][t] + redB[3][t];
    float a = BK[t];
    const float4* wk4 = (const float4*)(WK + (size_t)t * 128);
    const float4* ue4 = (const float4*)uel;
#pragma unroll 8
    for (int c = 0; c < 32; ++c) {
      float4 w = wk4[c], v = ue4[c];
      a += w.x * v.x + w.y * v.y + w.z * v.z + w.w * v.w;
    }
    a = fmaxf(a, 0.f);
    float sq = a * a;
#pragma unroll
    for (int m = 1; m <= 16; m <<= 1) sq += __shfl_xor(sq, m);
    float su = a / fmaxf(sqrtf(sq), 1e-12f) + suv;
    float sq2 = su * su;
#pragma unroll
    for (int m = 1; m <= 16; m <<= 1) sq2 += __shfl_xor(sq2, m);
    float tun = su / fmaxf(sqrtf(sq2), 1e-12f);
    float d0 = ubd[u * 3], d1 = ubd[u * 3 + 1], d2 = ubd[u * 3 + 2];
    float w0 = mw[0], w1 = mw[1], w2 = mw[2];
    float tw = d0 * w0 + d1 * w1 + d2 * w2;
    float dr = (r == 0 ? d0 : r == 1 ? d1 : d2);
    float wr = (r == 0 ? w0 : r == 1 ? w1 : w2);
    wtun[(size_t)(b * 3 + r) * 128 + t] = (dr * wr / (tw + FEPS)) * tun;
    tu[t] = tipv / (dr + FEPS);
  }
  __syncthreads();
  int ep = t & 127, hh = t >> 7;
  const float* Wb = ibW + (size_t)r * 16384;
  float pacc = 0.f;
  for (int e = hh * 64; e < hh * 64 + 64; ++e) pacc += tu[e] * Wb[e * 128 + ep];
  redA[hh][ep] = pacc;
  __syncthreads();
  if (hh == 0) proj[(size_t)(b * 3 + r) * 128 + ep] = redA[0][ep] + redA[1][ep];
}

// ---------------------------------------------------------------------------
// K5: uf[b] = (sum_r wtun[b,r]) @ W ; per-b uf^2 partial
__global__ void k_uf(const float* __restrict__ wtun, const float* __restrict__ Wm,
                     float* __restrict__ uf, float* __restrict__ uf2p) {
  int b = blockIdx.x, t = threadIdx.x;  // 128
  __shared__ float comb[128];
  __shared__ float part[2];
  comb[t] = wtun[(size_t)(b * 3) * 128 + t] + wtun[(size_t)(b * 3 + 1) * 128 + t] +
            wtun[(size_t)(b * 3 + 2) * 128 + t];
  __syncthreads();
  float acc = 0.f;
  for (int e = 0; e < 128; ++e) acc += comb[e] * Wm[e * 128 + t];
  uf[(size_t)b * 128 + t] = acc;
  float sq = acc * acc;
#pragma unroll
  for (int m = 1; m <= 32; m <<= 1) sq += __shfl_xor(sq, m);
  if ((t & 63) == 0) part[t >> 6] = sq;
  __syncthreads();
  if (t == 0) uf2p[b] = part[0] + part[1];
}

// ---------------------------------------------------------------------------
// K6: one wave per (b,l): score1 + LAMB*score2/R ; itf^2 partial per block
__global__ void k_score(const int* __restrict__ item, const float* __restrict__ itemf,
                        const float* __restrict__ uf, const float* __restrict__ tip,
                        const float* __restrict__ proj, float* __restrict__ out,
                        float* __restrict__ itf2p) {
  int t = threadIdx.x, wid = t >> 6, lane = t & 63;
  int idx = blockIdx.x * 4 + wid;  // < 51200
  int b = idx / NL;
  int it = item[idx];
  float2 av = ((const float2*)(itemf + (size_t)it * 128))[lane];
  float2 cv = ((const float2*)(uf + (size_t)b * 128))[lane];
  float s1 = av.x * cv.x + av.y * cv.y;
  float sqi = av.x * av.x + av.y * av.y;
  float s2 = 0.f;
#pragma unroll
  for (int r = 0; r < 3; ++r) {
    float2 tv = ((const float2*)(tip + ((size_t)r * NI + it) * 128))[lane];
    float2 pv = ((const float2*)(proj + (size_t)(b * 3 + r) * 128))[lane];
    s2 += tv.x * pv.x + tv.y * pv.y;
  }
#pragma unroll
  for (int m = 1; m <= 32; m <<= 1) {
    s1 += __shfl_xor(s1, m);
    s2 += __shfl_xor(s2, m);
    sqi += __shfl_xor(sqi, m);
  }
  if (lane == 0) out[idx] = s1 + 0.5f * (s2 * (1.f / 3.f));
  __shared__ float sh[4];
  if (lane == 0) sh[wid] = sqi;
  __syncthreads();
  if (t == 0) itf2p[blockIdx.x] = sh[0] + sh[1] + sh[2] + sh[3];
}

// ---------------------------------------------------------------------------
// K7: L2_loss = 1e-4 * (100 * sum uf^2 + sum itf^2)
__global__ void k_final(const float* __restrict__ itf2p, const float* __restrict__ uf2p,
                        float* __restrict__ out) {
  int t = threadIdx.x;  // 256
  float v = 0.f;
  for (int i = t; i < 12800; i += 256) v += itf2p[i];
  float vu = 0.f;
  for (int i = t; i < NB; i += 256) vu += uf2p[i];
  v += 100.f * vu;
#pragma unroll
  for (int m = 1; m <= 32; m <<= 1) v += __shfl_xor(v, m);
  __shared__ float sh[4];
  if ((t & 63) == 0) sh[t >> 6] = v;
  __syncthreads();
  if (t == 0) out[NB * NL] = 1e-4f * (sh[0] + sh[1] + sh[2] + sh[3]);
}

// ---------------------------------------------------------------------------
extern "C" void kernel_launch(void* const* d_in, const int* in_sizes, int n_in,
                              void* d_out, int out_size, void* d_ws, size_t ws_size,
                              hipStream_t stream) {
  (void)in_sizes; (void)n_in; (void)out_size; (void)ws_size;
  const int* user = (const int*)d_in[0];
  const int* item = (const int*)d_in[1];
  const float* uemb = (const float*)d_in[2];
  const float* iemb = (const float*)d_in[3];
  const float* mw = (const float*)d_in[4];
  const float* ibW = (const float*)d_in[5];
  const float* ipW = (const float*)d_in[6];
  const float* Wm = (const float*)d_in[7];
  const float* WK = (const float*)d_in[8];
  const float* BK = (const float*)d_in[9];
  const float* tm = (const float*)d_in[10];
  const float* relm = (const float*)d_in[11];
  const float* ig = (const float*)d_in[12];
  const float* igd = (const float*)d_in[13];
  const float* ubd = (const float*)d_in[14];
  float* out = (float*)d_out;
  float* ws = (float*)d_ws;
  unsigned long long* bmT = (unsigned long long*)(ws + WS_BMT);

  k_bmm_si<<<3072, 256, 0, stream>>>(iemb, ipW, uemb, Wm, WK, BK,
                                     ws + WS_EMBW, ws + WS_UEW, ws + WS_SI);
  k_scan<<<NU + NR * NI, 256, 0, stream>>>(tm, ig, igd, ws + WS_EMBW, bmT, ws + WS_TIP);
  k_itemf_csc<<<NI, 256, 0, stream>>>(bmT, ws + WS_UEW, ws + WS_ITEMF);
  k_user<<<NR * NB, 256, 0, stream>>>(user, relm, ws + WS_SI, ws + WS_TIP, uemb, WK, BK,
                                      ibW, ubd, mw, ws + WS_WTUN, ws + WS_PROJ);
  k_uf<<<NB, 128, 0, stream>>>(ws + WS_WTUN, Wm, ws + WS_UF, ws + WS_UF2P);
  k_score<<<12800, 256, 0, stream>>>(item, ws + WS_ITEMF, ws + WS_UF, ws + WS_TIP,
                                     ws + WS_PROJ, out, ws + WS_ITF2P);
  k_final<<<1, 256, 0, stream>>>(ws + WS_ITF2P, ws + WS_UF2P, out);
}